// Round 12
// baseline (269.118 us; speedup 1.0000x reference)
//
#include <hip/hip_runtime.h>
#include <math.h>

#define MIN_NORM 1e-15f
#define MAXNORM  0.996f          /* (1 - 4e-3)/sqrt(c), c=1 */
#define ARTANH_CLIP 0.99999988f  /* float(1.0 - 1e-7) */

typedef __bf16 bf16x8 __attribute__((ext_vector_type(8)));
typedef float  f32x4  __attribute__((ext_vector_type(4)));

union FragU { ushort u[8]; uint4 q; bf16x8 v; };

__device__ __forceinline__ float wave_sum(float v) {
#pragma unroll
    for (int off = 32; off > 0; off >>= 1) v += __shfl_xor(v, off, 64);
    return v;
}

// x >= 0 always (norms / products of norms). tanh(x) = 1 - 2/(e^2x + 1).
__device__ __forceinline__ float tanh_fast(float x) {
    const float t = __expf(2.f * fminf(x, 15.f));
    return 1.f - 2.f / (t + 1.f);
}
// 0 <= x < 1. artanh(x) = 0.5*log((1+x)/(1-x)).
__device__ __forceinline__ float artanh_fast(float x) {
    x = fminf(x, ARTANH_CLIP);
    return 0.5f * __logf((1.f + x) / (1.f - x));
}

__device__ __forceinline__ float proj_factor(float n2) {
    float n = fmaxf(sqrtf(n2), MIN_NORM);
    return (n > MAXNORM) ? (MAXNORM / n) : 1.f;
}

__device__ __forceinline__ unsigned short f2bf(float f) {   // RNE
    unsigned u = __float_as_uint(f);
    return (unsigned short)((u + 0x7fffu + ((u >> 16) & 1u)) >> 16);
}
__device__ __forceinline__ float bf2f(unsigned short h) {
    return __uint_as_float((unsigned)h << 16);
}
__device__ __forceinline__ float bflo(unsigned u) { return __uint_as_float(u << 16); }
__device__ __forceinline__ float bfhi(unsigned u) { return __uint_as_float(u & 0xffff0000u); }

__device__ __forceinline__ void red16_f4(float4& v) {
#pragma unroll
    for (int off = 1; off < 16; off <<= 1) {
        v.x += __shfl_xor(v.x, off, 64);
        v.y += __shfl_xor(v.y, off, 64);
        v.z += __shfl_xor(v.z, off, 64);
        v.w += __shfl_xor(v.w, off, 64);
    }
}

// component (r&3) of float4 held by group (r>>2)
__device__ __forceinline__ float bcast_row(const float4& v, int r) {
    const int src = (r >> 2) << 4;
    const float a = __shfl(v.x, src, 64);
    const float b = __shfl(v.y, src, 64);
    const float c = __shfl(v.z, src, 64);
    const float d = __shfl(v.w, src, 64);
    const float lo = (r & 1) ? b : a;
    const float hi = (r & 1) ? d : c;
    return (r & 2) ? hi : lo;
}

// feature-permuted pack row: feature o lives at prow = 16*(o&7) + (o>>3),
// so acc tile ct / lane r15 holds feature 8*r15+ct (contiguous per lane).
__device__ __forceinline__ void pack_w4(const float4 w4, int o, int k, char* out) {
    ushort4 h, l;
    h.x = f2bf(w4.x); l.x = f2bf(w4.x - bf2f(h.x));
    h.y = f2bf(w4.y); l.y = f2bf(w4.y - bf2f(h.y));
    h.z = f2bf(w4.z); l.z = f2bf(w4.z - bf2f(h.z));
    h.w = f2bf(w4.w); l.w = f2bf(w4.w - bf2f(h.w));
    const int prow = ((o & 7) << 4) | (o >> 3);
    const unsigned byte = (unsigned)((prow << 8) + (k << 1)) ^ (unsigned)((prow & 7) << 4);
    *reinterpret_cast<ushort4*>(out + byte) = h;
    *reinterpret_cast<ushort4*>(out + 32768 + byte) = l;
}

// -------- fused setup: prep_w (blocks 0..31) + bias (block 32) + hist (33..) --------
__global__ __launch_bounds__(256)
void setup_kernel(const float* __restrict__ W1, const float* __restrict__ W2,
                  char* __restrict__ g1, char* __restrict__ g2,
                  const float* __restrict__ b1, const float* __restrict__ b2,
                  float* __restrict__ hb1, float* __restrict__ hb2,
                  const int* __restrict__ dst, int* __restrict__ cnt, int E) {
    const int b = blockIdx.x;
    if (b < 32) {
        const float* W = (b < 16) ? W1 : W2;
        char* out = (b < 16) ? g1 : g2;
        const int i = (((b & 15) * 256) + threadIdx.x) * 4;   // element index
        pack_w4(*reinterpret_cast<const float4*>(&W[i]), i >> 7, i & 127, out);
    } else if (b == 32) {
        if (threadIdx.x < 64) {
            const int lane = threadIdx.x;
#pragma unroll
            for (int j = 0; j < 2; ++j) {
                const float* bb = j ? b2 : b1;
                float* hb = j ? hb2 : hb1;
                float v0 = bb[lane], v1 = bb[lane + 64];
                float n2 = wave_sum(v0 * v0 + v1 * v1);
                float n = fmaxf(sqrtf(n2), MIN_NORM);
                float sc = tanh_fast(n) / n;
                sc *= proj_factor(sc * sc * n2);
                hb[lane] = v0 * sc;
                hb[lane + 64] = v1 * sc;
            }
        }
    } else {
        const int e = (b - 33) * 256 + threadIdx.x;
        if (e < E) atomicAdd(&cnt[dst[e]], 1);
    }
}

// -------- fused scan (one block): padded exclusive scan of ((cnt+3)&~3) --------
__global__ __launch_bounds__(1024)
void scan_fused(const int* __restrict__ cnt, int* __restrict__ ptr,
                int* __restrict__ cursor, int N) {
    __shared__ int s[1024];
    const int t = threadIdx.x;
    const int C = (N + 1023) >> 10;
    const int i0 = t * C;
    const int i1 = min(i0 + C, N);
    int sum = 0;
    for (int i = i0; i < i1; ++i) sum += (cnt[i] + 3) & ~3;
    s[t] = sum;
    __syncthreads();
#pragma unroll
    for (int off = 1; off < 1024; off <<= 1) {
        int add = (t >= off) ? s[t - off] : 0;
        __syncthreads();
        s[t] += add;
        __syncthreads();
    }
    int run = s[t] - sum;               // exclusive prefix of this chunk
    for (int i = i0; i < i1; ++i) {
        const int pc = (cnt[i] + 3) & ~3;
        ptr[i] = run;
        cursor[i] = run;
        run += pc;
    }
    if (t == 1023) ptr[N] = s[1023];    // total padded length
}

// packed edge: hi16 = src node id (N < 65536), lo16 = bf16(weight)
__global__ void scatter_kernel(const int* __restrict__ src, const int* __restrict__ dst,
                               const float* __restrict__ ew, int* __restrict__ cursor,
                               unsigned* __restrict__ epk, int E) {
    int e = blockIdx.x * blockDim.x + threadIdx.x;
    if (e >= E) return;
    int pos = atomicAdd(&cursor[dst[e]], 1);
    epk[pos] = ((unsigned)src[e] << 16) | (unsigned)f2bf(ew[e]);
}

// ---------------- MFMA fused linear ----------------
// 512-thread blocks (8 waves share a 64KB W stage; 2 blocks/CU co-resident so
// staging overlaps compute across blocks). Each wave runs <=1 sixteen-row tile.
// BF16IN: input exact in bf16 => lo(x)=0 => 2 MFMAs/step instead of 3.
template <bool PRELUDE, bool BF16IN, bool BF16OUT>
__global__ __launch_bounds__(512, 4)
void hyp_linear_tan_mfma(const void* __restrict__ xin, const char* __restrict__ gWpack,
                         const float* __restrict__ hb, void* __restrict__ xtan,
                         int n_rows) {
    __shared__ __align__(16) char sW[65536];   // [0,32K)=hi swz, [32K,64K)=lo swz

    const int tid = threadIdx.x;
    const int lane = tid & 63, wid = tid >> 6;
    const int r15 = lane & 15, g = lane >> 4;

    const int tiles = (n_rows + 15) >> 4;
    const int tile = blockIdx.x * 8 + wid;
    const bool active = (tile < tiles);
    const int rowbase = tile << 4;
    const int myrow = rowbase + r15;
    const bool rok = active && (myrow < n_rows);

    // 1) issue x loads first (latency overlaps the staging below)
    float4 xa[4], xb[4];
    uint4 xu[4];
    if (BF16IN) {
        const char* xr = (const char*)xin + (size_t)myrow * 256 + g * 16;
#pragma unroll
        for (int kc = 0; kc < 4; ++kc)
            xu[kc] = rok ? *reinterpret_cast<const uint4*>(xr + kc * 64)
                         : make_uint4(0u, 0u, 0u, 0u);
    } else {
        const float* xr = (const float*)xin + (size_t)myrow * 128 + g * 8;
#pragma unroll
        for (int kc = 0; kc < 4; ++kc) {
            if (rok) {
                xa[kc] = *reinterpret_cast<const float4*>(xr + kc * 32);
                xb[kc] = *reinterpret_cast<const float4*>(xr + kc * 32 + 4);
            } else {
                xa[kc] = make_float4(0.f, 0.f, 0.f, 0.f);
                xb[kc] = xa[kc];
            }
        }
    }

    // 2) stage W pack (64KB / 512 threads = 8 uint4 each)
    {
        const uint4* gsrc = reinterpret_cast<const uint4*>(gWpack);
        uint4* ldst = reinterpret_cast<uint4*>(sW);
#pragma unroll
        for (int i = 0; i < 8; ++i) ldst[tid + i * 512] = gsrc[tid + i * 512];
    }

    // 3) bias fragment: yb[ct] = hb[8*r15 + ct]
    float yb[8];
    {
        const float4 yba = *reinterpret_cast<const float4*>(&hb[r15 * 8]);
        const float4 ybb = *reinterpret_cast<const float4*>(&hb[r15 * 8 + 4]);
        yb[0] = yba.x; yb[1] = yba.y; yb[2] = yba.z; yb[3] = yba.w;
        yb[4] = ybb.x; yb[5] = ybb.y; yb[6] = ybb.z; yb[7] = ybb.w;
    }
    float y2p = 0.f;
#pragma unroll
    for (int t = 0; t < 8; ++t) y2p += yb[t] * yb[t];
#pragma unroll
    for (int off = 1; off < 16; off <<= 1) y2p += __shfl_xor(y2p, off, 64);
    const float y2 = y2p;

    __syncthreads();
    if (!active) return;

    // 4) A-fragments + row norm
    bf16x8 ah[4], al[4];
    float ss = 0.f;
    if (BF16IN) {
#pragma unroll
        for (int kc = 0; kc < 4; ++kc) {
            FragU fu; fu.q = xu[kc];
            ah[kc] = fu.v;
            const uint4 u = xu[kc];
            float f0 = bflo(u.x), f1 = bfhi(u.x), f2_ = bflo(u.y), f3 = bfhi(u.y);
            float f4 = bflo(u.z), f5 = bfhi(u.z), f6 = bflo(u.w), f7 = bfhi(u.w);
            ss += f0 * f0 + f1 * f1 + f2_ * f2_ + f3 * f3
                + f4 * f4 + f5 * f5 + f6 * f6 + f7 * f7;
        }
    } else {
#pragma unroll
        for (int kc = 0; kc < 4; ++kc) {
            const float4 a = xa[kc], b = xb[kc];
            ss += a.x * a.x + a.y * a.y + a.z * a.z + a.w * a.w
                + b.x * b.x + b.y * b.y + b.z * b.z + b.w * b.w;
            ah[kc][0] = (__bf16)a.x; al[kc][0] = (__bf16)(a.x - (float)ah[kc][0]);
            ah[kc][1] = (__bf16)a.y; al[kc][1] = (__bf16)(a.y - (float)ah[kc][1]);
            ah[kc][2] = (__bf16)a.z; al[kc][2] = (__bf16)(a.z - (float)ah[kc][2]);
            ah[kc][3] = (__bf16)a.w; al[kc][3] = (__bf16)(a.w - (float)ah[kc][3]);
            ah[kc][4] = (__bf16)b.x; al[kc][4] = (__bf16)(b.x - (float)ah[kc][4]);
            ah[kc][5] = (__bf16)b.y; al[kc][5] = (__bf16)(b.y - (float)ah[kc][5]);
            ah[kc][6] = (__bf16)b.z; al[kc][6] = (__bf16)(b.z - (float)ah[kc][6]);
            ah[kc][7] = (__bf16)b.w; al[kc][7] = (__bf16)(b.w - (float)ah[kc][7]);
        }
    }
    ss += __shfl_xor(ss, 16, 64);
    ss += __shfl_xor(ss, 32, 64);   // n2 of row rowbase + (lane&15)

    f32x4 acc[8];
#pragma unroll
    for (int ct = 0; ct < 8; ++ct) acc[ct] = (f32x4){0.f, 0.f, 0.f, 0.f};

    const unsigned lswz = (unsigned)((r15 & 7) << 4);
#pragma unroll
    for (int kc = 0; kc < 4; ++kc) {
#pragma unroll
        for (int ct = 0; ct < 8; ++ct) {
            const unsigned byte =
                ((unsigned)((ct << 12) + (r15 << 8) + (kc << 6) + (g << 4))) ^ lswz;
            FragU bh, bl;
            bh.q = *reinterpret_cast<const uint4*>(sW + byte);
            bl.q = *reinterpret_cast<const uint4*>(sW + 32768 + byte);
            acc[ct] = __builtin_amdgcn_mfma_f32_16x16x32_bf16(ah[kc], bh.v, acc[ct], 0, 0, 0);
            acc[ct] = __builtin_amdgcn_mfma_f32_16x16x32_bf16(ah[kc], bl.v, acc[ct], 0, 0, 0);
            if (!BF16IN)
                acc[ct] = __builtin_amdgcn_mfma_f32_16x16x32_bf16(al[kc], bh.v, acc[ct], 0, 0, 0);
        }
    }

    // ---- packed reductions: rawn2 and xyraw per reg-row ----
    float4 r2 = make_float4(0.f, 0.f, 0.f, 0.f);
    float4 xyv = make_float4(0.f, 0.f, 0.f, 0.f);
#pragma unroll
    for (int ct = 0; ct < 8; ++ct) {
        r2.x += acc[ct][0] * acc[ct][0];
        r2.y += acc[ct][1] * acc[ct][1];
        r2.z += acc[ct][2] * acc[ct][2];
        r2.w += acc[ct][3] * acc[ct][3];
        xyv.x += acc[ct][0] * yb[ct];
        xyv.y += acc[ct][1] * yb[ct];
        xyv.z += acc[ct][2] * yb[ct];
        xyv.w += acc[ct][3] * yb[ct];
    }
    red16_f4(r2);
    red16_f4(xyv);

    // ---- per-row scalar chain, ONE row per lane (row = lane&15) ----
    const float rn2 = bcast_row(r2, r15);
    const float xyr = bcast_row(xyv, r15);
    const float n2v = ss;

    const float n = fmaxf(sqrtf(n2v), MIN_NORM);
    float sc = 1.f;
    if (PRELUDE) {
        sc = tanh_fast(n) / n;
        sc *= proj_factor(sc * sc * n2v);
    }
    const float xn = fmaxf(sc * n, MIN_NORM);
    const float mxn = fmaxf(sc * sqrtf(rn2), MIN_NORM);
    const float s = tanh_fast(mxn / xn * artanh_fast(xn));
    const float sl0 = (s * sc) / mxn;
    float m2 = rn2 * sl0 * sl0;
    const float f = proj_factor(m2);
    const float scl = sl0 * f;
    m2 *= f * f;
    const float xy = scl * xyr;
    const float cx = 1.f + 2.f * xy + y2;
    const float cy = 1.f - m2;
    const float rdn = 1.f / fmaxf(1.f + 2.f * xy + m2 * y2, MIN_NORM);
    const float A = cx * scl * rdn;             // o = A*raw + B*yb
    const float B = cy * rdn;
    const float on2 = A * A * rn2 + 2.f * A * B * xyr + B * B * y2;
    const float f2 = proj_factor(on2);
    const float onn = fmaxf(sqrtf(on2) * f2, MIN_NORM);
    const float slg = artanh_fast(onn) / onn;
    const float P = slg * f2 * A;
    const float Q = slg * f2 * B;

#pragma unroll
    for (int reg = 0; reg < 4; ++reg) {
        const float Pr = __shfl(P, 4 * g + reg, 64);
        const float Qr = __shfl(Q, 4 * g + reg, 64);
        const int row = rowbase + 4 * g + reg;
        if (row < n_rows) {
            float v[8];
#pragma unroll
            for (int ct = 0; ct < 8; ++ct)
                v[ct] = fmaf(Pr, acc[ct][reg], Qr * yb[ct]);
            if (BF16OUT) {
                uint4 pk;
                pk.x = (unsigned)f2bf(v[0]) | ((unsigned)f2bf(v[1]) << 16);
                pk.y = (unsigned)f2bf(v[2]) | ((unsigned)f2bf(v[3]) << 16);
                pk.z = (unsigned)f2bf(v[4]) | ((unsigned)f2bf(v[5]) << 16);
                pk.w = (unsigned)f2bf(v[6]) | ((unsigned)f2bf(v[7]) << 16);
                *reinterpret_cast<uint4*>((char*)xtan + (size_t)row * 256 + r15 * 16) = pk;
            } else {
                float* orow = (float*)xtan + (size_t)row * 128 + r15 * 8;
                *reinterpret_cast<float4*>(orow) = make_float4(v[0], v[1], v[2], v[3]);
                *reinterpret_cast<float4*>(orow + 4) = make_float4(v[4], v[5], v[6], v[7]);
            }
        }
    }
}

// ---------------- gather aggregate + fused hyp_act ----------------
// 16 lanes per row (uint4 = 8 bf16 features each). Padded CSR: every row's
// segment length % 4 == 0 and pad entries are {src 0, w +0.0} -> all four
// wave-quarters run identical, branch-free iteration counts.
template <bool BF16OUT>
__global__ __launch_bounds__(256)
void gather_act(const char* __restrict__ xt, const int* __restrict__ ptr,
                const unsigned* __restrict__ epk, void* __restrict__ out, int n_rows) {
    const int v = blockIdx.x * 4 + (threadIdx.x >> 6);
    if (v >= n_rows) return;
    const int lane = threadIdx.x & 63;
    const int q = lane >> 4, t = lane & 15;
    const char* xtl = xt + (t << 4);
    const int beg = ptr[v];
    const int it = (ptr[v + 1] - beg) >> 2;   // identical for all 4 quarters

    float acc[8];
#pragma unroll
    for (int j = 0; j < 8; ++j) acc[j] = 0.f;

    const unsigned* ep = epk + beg + q;
    unsigned p = (it > 0) ? ep[0] : 0u;
    for (int k = 1; k <= it; ++k) {
        const uint4 u = *reinterpret_cast<const uint4*>(xtl + ((p >> 16) << 8));
        const unsigned pn = ep[k * 4];        // buffer has a +16-word tail guard
        const float w = __uint_as_float(p << 16);
        acc[0] = fmaf(w, bflo(u.x), acc[0]);
        acc[1] = fmaf(w, bfhi(u.x), acc[1]);
        acc[2] = fmaf(w, bflo(u.y), acc[2]);
        acc[3] = fmaf(w, bfhi(u.y), acc[3]);
        acc[4] = fmaf(w, bflo(u.z), acc[4]);
        acc[5] = fmaf(w, bfhi(u.z), acc[5]);
        acc[6] = fmaf(w, bflo(u.w), acc[6]);
        acc[7] = fmaf(w, bfhi(u.w), acc[7]);
        p = pn;
    }

    // reduce across quarters: every lane gets full sums for features 8t+j
#pragma unroll
    for (int j = 0; j < 8; ++j) {
        acc[j] += __shfl_xor(acc[j], 16, 64);
        acc[j] += __shfl_xor(acc[j], 32, 64);
    }

    // n2 over the 128 features (partitioned by t; quarters identical)
    float s = 0.f;
#pragma unroll
    for (int j = 0; j < 8; ++j) s += acc[j] * acc[j];
#pragma unroll
    for (int off = 1; off < 16; off <<= 1) s += __shfl_xor(s, off, 64);
    const float n2 = s;

    // h = proj(expmap0(agg)); x = relu(logmap0(h)); out = proj(expmap0(x))
    float n = fmaxf(sqrtf(n2), MIN_NORM);
    float sc = tanh_fast(n) / n;
    float hn2 = sc * sc * n2;
    float f = proj_factor(hn2);
    sc *= f; hn2 *= f * f;
    float hn = fmaxf(sqrtf(hn2), MIN_NORM);
    float sl = artanh_fast(hn) / hn;
    const float scl1 = sc * sl;

    float x[8];
    float s2 = 0.f;
#pragma unroll
    for (int j = 0; j < 8; ++j) {
        x[j] = fmaxf(acc[j] * scl1, 0.f);
        s2 += x[j] * x[j];
    }
#pragma unroll
    for (int off = 1; off < 16; off <<= 1) s2 += __shfl_xor(s2, off, 64);
    float nb = fmaxf(sqrtf(s2), MIN_NORM);
    float scb = tanh_fast(nb) / nb;
    scb *= proj_factor(scb * scb * s2);

    // store: quarter q writes features 8t+2q, 8t+2q+1 (64 lanes cover the row)
    const float o0 = x[2 * q] * scb, o1 = x[2 * q + 1] * scb;
    if (BF16OUT) {
        const unsigned pk = (unsigned)f2bf(o0) | ((unsigned)f2bf(o1) << 16);
        *reinterpret_cast<unsigned*>((char*)out + (size_t)v * 256 + t * 16 + q * 4) = pk;
    } else {
        *reinterpret_cast<float2*>((float*)out + (size_t)v * 128 + t * 8 + q * 2) =
            make_float2(o0, o1);
    }
}

// ---------------- fallback (atomic path, f32 x_tan) ----------------
__global__ __launch_bounds__(256)
void agg_edges(const float* __restrict__ xtan, const int* __restrict__ src,
               const int* __restrict__ dst, const float* __restrict__ ew,
               float* __restrict__ agg, int n_edges) {
    int gt = blockIdx.x * blockDim.x + threadIdx.x;
    int e = gt >> 5;
    if (e >= n_edges) return;
    int c = (gt & 31) << 2;
    int sN = src[e], dN = dst[e];
    float w = ew[e];
    const float4 v = *reinterpret_cast<const float4*>(&xtan[(size_t)sN * 128 + c]);
    float* ap = &agg[(size_t)dN * 128 + c];
    atomicAdd(ap + 0, w * v.x);
    atomicAdd(ap + 1, w * v.y);
    atomicAdd(ap + 2, w * v.z);
    atomicAdd(ap + 3, w * v.w);
}

__global__ __launch_bounds__(256)
void hyp_act_kernel(const float* __restrict__ in, float* __restrict__ out, int n_rows) {
    int row = blockIdx.x * 4 + (threadIdx.x >> 6);
    if (row >= n_rows) return;
    int lane = threadIdx.x & 63;
    int l2 = lane << 1;
    const float2 v = *reinterpret_cast<const float2*>(&in[(size_t)row * 128 + l2]);
    float a0 = v.x, a1 = v.y;
    float n2 = wave_sum(a0 * a0 + a1 * a1);
    float n = fmaxf(sqrtf(n2), MIN_NORM);
    float sc = tanh_fast(n) / n;
    float hn2 = sc * sc * n2;
    float f = proj_factor(hn2);
    sc *= f; hn2 *= f * f;
    float h0 = a0 * sc, h1 = a1 * sc;
    float hn = fmaxf(sqrtf(hn2), MIN_NORM);
    float sl = artanh_fast(hn) / hn;
    float x0 = fmaxf(h0 * sl, 0.f), x1 = fmaxf(h1 * sl, 0.f);
    float n2b = wave_sum(x0 * x0 + x1 * x1);
    float nb = fmaxf(sqrtf(n2b), MIN_NORM);
    float scb = tanh_fast(nb) / nb;
    scb *= proj_factor(scb * scb * n2b);
    *reinterpret_cast<float2*>(&out[(size_t)row * 128 + l2]) =
        make_float2(x0 * scb, x1 * scb);
}

__global__ void bias_kernel(const float* __restrict__ b1, const float* __restrict__ b2,
                            float* __restrict__ hb1, float* __restrict__ hb2) {
    int lane = threadIdx.x;
#pragma unroll
    for (int j = 0; j < 2; ++j) {
        const float* b = j ? b2 : b1;
        float* hb = j ? hb2 : hb1;
        float v0 = b[lane], v1 = b[lane + 64];
        float n2 = wave_sum(v0 * v0 + v1 * v1);
        float n = fmaxf(sqrtf(n2), MIN_NORM);
        float sc = tanh_fast(n) / n;
        sc *= proj_factor(sc * sc * n2);
        hb[lane] = v0 * sc;
        hb[lane + 64] = v1 * sc;
    }
}

__global__ void prep_w(const float* __restrict__ W1, const float* __restrict__ W2,
                       char* __restrict__ g1, char* __restrict__ g2) {
    const int b = blockIdx.x;
    const float* W = (b < 16) ? W1 : W2;
    char* out = (b < 16) ? g1 : g2;
    const int i = (((b & 15) * 256) + threadIdx.x) * 4;
    pack_w4(*reinterpret_cast<const float4*>(&W[i]), i >> 7, i & 127, out);
}

extern "C" void kernel_launch(void* const* d_in, const int* in_sizes, int n_in,
                              void* d_out, int out_size, void* d_ws, size_t ws_size,
                              hipStream_t stream) {
    const float* x   = (const float*)d_in[0];
    const int*   src = (const int*)d_in[1];
    const int*   dst = (const int*)d_in[2];
    const float* ew  = (const float*)d_in[3];
    const float* W1  = (const float*)d_in[4];
    const float* b1  = (const float*)d_in[5];
    const float* W2  = (const float*)d_in[6];
    const float* b2  = (const float*)d_in[7];

    const int N = in_sizes[0] / 128;
    const int E = in_sizes[1];
    float* fout = (float*)d_out;

    const int tiles = (N + 15) >> 4;
    const int lin_grid = (tiles + 7) / 8;     // 8 waves (512 thr) per block
    const int nbE = (E + 255) / 256;

    const size_t epk_words = (size_t)E + 3 * (size_t)N + 16;  // padded CSR + tail guard

    // main-path ws: gW(128K) + hb(1K) + xtA,xtB (bf16) + [epk|cnt] + ptr + cursor
    const size_t need = 131072 + 1024
                      + (size_t)N * 256 * 2
                      + (epk_words + N) * 4
                      + ((size_t)(N + 1) + N) * 4
                      + 1024;

    if (ws_size >= need) {
        char*  base  = (char*)d_ws;
        char*  gW1p  = base;
        char*  gW2p  = base + 65536;
        float* hb1   = (float*)(base + 131072);       // 16B-aligned
        float* hb2   = hb1 + 128;
        char*  xtA   = base + 131072 + 1024;          // N*128 bf16
        char*  xtB   = xtA + (size_t)N * 256;         // N*128 bf16
        unsigned* epk = (unsigned*)(xtB + (size_t)N * 256);
        int* cnt     = (int*)(epk + epk_words);       // adjacent: one memset
        int* ptr     = cnt + N;
        int* cursor  = ptr + (N + 1);

        // zero epk (pads must be {src 0, w 0}) and cnt in one shot
        hipMemsetAsync(epk, 0, (epk_words + N) * 4, stream);
        setup_kernel<<<33 + nbE, 256, 0, stream>>>(W1, W2, gW1p, gW2p,
                                                   b1, b2, hb1, hb2, dst, cnt, E);
        scan_fused<<<1, 1024, 0, stream>>>(cnt, ptr, cursor, N);
        scatter_kernel<<<nbE, 256, 0, stream>>>(src, dst, ew, cursor, epk, E);

        // layer 1: x(f32) -> xtA(bf16) -> h1 = xtB(bf16)
        hyp_linear_tan_mfma<true, false, true><<<lin_grid, 512, 0, stream>>>(x, gW1p, hb1, xtA, N);
        gather_act<true><<<(N + 3) / 4, 256, 0, stream>>>(xtA, ptr, epk, xtB, N);
        // layer 2: h1(bf16) -> x_tan2 = xtA(bf16, dead) -> final(f32, d_out)
        hyp_linear_tan_mfma<false, true, true><<<lin_grid, 512, 0, stream>>>(xtB, gW2p, hb2, xtA, N);
        gather_act<false><<<(N + 3) / 4, 256, 0, stream>>>(xtA, ptr, epk, fout, N);
    } else {
        // fallback: f32 atomic-scatter path
        char*  gW1p = (char*)d_ws;
        char*  gW2p = gW1p + 65536;
        float* hb1  = (float*)(gW2p + 65536);
        float* hb2  = hb1 + 128;
        float* nbuf = hb2 + 128;
        const size_t node_bytes = (size_t)N * 128 * sizeof(float);
        const int agg_blocks = (int)(((size_t)E * 32 + 255) / 256);
        const int row_blocks = (N + 3) / 4;

        prep_w<<<32, 256, 0, stream>>>(W1, W2, gW1p, gW2p);
        bias_kernel<<<1, 64, 0, stream>>>(b1, b2, hb1, hb2);
        hyp_linear_tan_mfma<true, false, false><<<lin_grid, 512, 0, stream>>>(x, gW1p, hb1, fout, N);
        hipMemsetAsync(nbuf, 0, node_bytes, stream);
        agg_edges<<<agg_blocks, 256, 0, stream>>>(fout, src, dst, ew, nbuf, E);
        hyp_act_kernel<<<row_blocks, 256, 0, stream>>>(nbuf, nbuf, N);
        hyp_linear_tan_mfma<false, false, false><<<lin_grid, 512, 0, stream>>>(nbuf, gW2p, hb2, fout, N);
        hipMemsetAsync(fout, 0, node_bytes, stream);
        agg_edges<<<agg_blocks, 256, 0, stream>>>(fout, src, dst, ew, nbuf, E);
        hyp_act_kernel<<<row_blocks, 256, 0, stream>>>(nbuf, fout, N);
    }
}

// Round 13
// 168.639 us; speedup vs baseline: 1.5958x; 1.5958x over previous
//
#include <hip/hip_runtime.h>
#include <math.h>

#define MIN_NORM 1e-15f
#define MAXNORM  0.996f          /* (1 - 4e-3)/sqrt(c), c=1 */
#define ARTANH_CLIP 0.99999988f  /* float(1.0 - 1e-7) */

typedef __bf16 bf16x8 __attribute__((ext_vector_type(8)));
typedef float  f32x4  __attribute__((ext_vector_type(4)));

union FragU { ushort u[8]; uint4 q; bf16x8 v; };

__device__ __forceinline__ float wave_sum(float v) {
#pragma unroll
    for (int off = 32; off > 0; off >>= 1) v += __shfl_xor(v, off, 64);
    return v;
}

// x >= 0 always (norms / products of norms). tanh(x) = 1 - 2/(e^2x + 1).
__device__ __forceinline__ float tanh_fast(float x) {
    const float t = __expf(2.f * fminf(x, 15.f));
    return 1.f - 2.f / (t + 1.f);
}
// 0 <= x < 1. artanh(x) = 0.5*log((1+x)/(1-x)).
__device__ __forceinline__ float artanh_fast(float x) {
    x = fminf(x, ARTANH_CLIP);
    return 0.5f * __logf((1.f + x) / (1.f - x));
}

__device__ __forceinline__ float proj_factor(float n2) {
    float n = fmaxf(sqrtf(n2), MIN_NORM);
    return (n > MAXNORM) ? (MAXNORM / n) : 1.f;
}

__device__ __forceinline__ unsigned short f2bf(float f) {   // RNE
    unsigned u = __float_as_uint(f);
    return (unsigned short)((u + 0x7fffu + ((u >> 16) & 1u)) >> 16);
}
__device__ __forceinline__ float bf2f(unsigned short h) {
    return __uint_as_float((unsigned)h << 16);
}
__device__ __forceinline__ float bflo(unsigned u) { return __uint_as_float(u << 16); }
__device__ __forceinline__ float bfhi(unsigned u) { return __uint_as_float(u & 0xffff0000u); }

__device__ __forceinline__ void red16_f4(float4& v) {
#pragma unroll
    for (int off = 1; off < 16; off <<= 1) {
        v.x += __shfl_xor(v.x, off, 64);
        v.y += __shfl_xor(v.y, off, 64);
        v.z += __shfl_xor(v.z, off, 64);
        v.w += __shfl_xor(v.w, off, 64);
    }
}

// component (r&3) of float4 held by group (r>>2)
__device__ __forceinline__ float bcast_row(const float4& v, int r) {
    const int src = (r >> 2) << 4;
    const float a = __shfl(v.x, src, 64);
    const float b = __shfl(v.y, src, 64);
    const float c = __shfl(v.z, src, 64);
    const float d = __shfl(v.w, src, 64);
    const float lo = (r & 1) ? b : a;
    const float hi = (r & 1) ? d : c;
    return (r & 2) ? hi : lo;
}

// feature-permuted pack row: feature o lives at prow = 16*(o&7) + (o>>3),
// so acc tile ct / lane r15 holds feature 8*r15+ct (contiguous per lane).
__device__ __forceinline__ void pack_w4(const float4 w4, int o, int k, char* out) {
    ushort4 h, l;
    h.x = f2bf(w4.x); l.x = f2bf(w4.x - bf2f(h.x));
    h.y = f2bf(w4.y); l.y = f2bf(w4.y - bf2f(h.y));
    h.z = f2bf(w4.z); l.z = f2bf(w4.z - bf2f(h.z));
    h.w = f2bf(w4.w); l.w = f2bf(w4.w - bf2f(h.w));
    const int prow = ((o & 7) << 4) | (o >> 3);
    const unsigned byte = (unsigned)((prow << 8) + (k << 1)) ^ (unsigned)((prow & 7) << 4);
    *reinterpret_cast<ushort4*>(out + byte) = h;
    *reinterpret_cast<ushort4*>(out + 32768 + byte) = l;
}

// -------- fused setup: prep_w (blocks 0..31) + bias (block 32) + hist (33..) --------
__global__ __launch_bounds__(256)
void setup_kernel(const float* __restrict__ W1, const float* __restrict__ W2,
                  char* __restrict__ g1, char* __restrict__ g2,
                  const float* __restrict__ b1, const float* __restrict__ b2,
                  float* __restrict__ hb1, float* __restrict__ hb2,
                  const int* __restrict__ dst, int* __restrict__ cnt, int E) {
    const int b = blockIdx.x;
    if (b < 32) {
        const float* W = (b < 16) ? W1 : W2;
        char* out = (b < 16) ? g1 : g2;
        const int i = (((b & 15) * 256) + threadIdx.x) * 4;   // element index
        pack_w4(*reinterpret_cast<const float4*>(&W[i]), i >> 7, i & 127, out);
    } else if (b == 32) {
        if (threadIdx.x < 64) {
            const int lane = threadIdx.x;
#pragma unroll
            for (int j = 0; j < 2; ++j) {
                const float* bb = j ? b2 : b1;
                float* hb = j ? hb2 : hb1;
                float v0 = bb[lane], v1 = bb[lane + 64];
                float n2 = wave_sum(v0 * v0 + v1 * v1);
                float n = fmaxf(sqrtf(n2), MIN_NORM);
                float sc = tanh_fast(n) / n;
                sc *= proj_factor(sc * sc * n2);
                hb[lane] = v0 * sc;
                hb[lane + 64] = v1 * sc;
            }
        }
    } else {
        const int e = (b - 33) * 256 + threadIdx.x;
        if (e < E) atomicAdd(&cnt[dst[e]], 1);
    }
}

// ---------------- CSR build: distributed scan over PADDED counts ----------------

// block-level exclusive scan of pc[i] = (cnt[i]+3)&~3
__global__ void scan1(const int* __restrict__ cnt, int* __restrict__ ptr,
                      int* __restrict__ bsum, int N) {
    __shared__ int s[256];
    const int t = threadIdx.x;
    const int i = blockIdx.x * 256 + t;
    int v = (i < N) ? ((cnt[i] + 3) & ~3) : 0;
    s[t] = v;
    __syncthreads();
#pragma unroll
    for (int off = 1; off < 256; off <<= 1) {
        int add = (t >= off) ? s[t - off] : 0;
        __syncthreads();
        s[t] += add;
        __syncthreads();
    }
    if (i < N) ptr[i] = s[t] - v;          // exclusive within block
    if (t == 255) bsum[blockIdx.x] = s[255];
}

// scan of block sums; also stores grand total at bscan[256]
__global__ void scan2(const int* __restrict__ bsum, int* __restrict__ bscan, int nb) {
    __shared__ int s[256];
    const int t = threadIdx.x;
    int v = (t < nb) ? bsum[t] : 0;
    s[t] = v;
    __syncthreads();
#pragma unroll
    for (int off = 1; off < 256; off <<= 1) {
        int add = (t >= off) ? s[t - off] : 0;
        __syncthreads();
        s[t] += add;
        __syncthreads();
    }
    bscan[t] = s[t] - v;                   // exclusive block offsets
    if (t == 255) bscan[256] = s[255];     // total padded length
}

__global__ void scan3(const int* __restrict__ bscan, int* __restrict__ ptr,
                      int* __restrict__ cursor, int N) {
    const int i = blockIdx.x * blockDim.x + threadIdx.x;
    if (i < N) {
        const int p = ptr[i] + bscan[i >> 8];
        ptr[i] = p;
        cursor[i] = p;
    }
    if (i == 0) ptr[N] = bscan[256];
}

// packed edge: hi16 = src node id (N < 65536), lo16 = bf16(weight)
__global__ void scatter_kernel(const int* __restrict__ src, const int* __restrict__ dst,
                               const float* __restrict__ ew, int* __restrict__ cursor,
                               unsigned* __restrict__ epk, int E) {
    int e = blockIdx.x * blockDim.x + threadIdx.x;
    if (e >= E) return;
    int pos = atomicAdd(&cursor[dst[e]], 1);
    epk[pos] = ((unsigned)src[e] << 16) | (unsigned)f2bf(ew[e]);
}

// ---------------- MFMA fused linear ----------------
// 512-thread blocks (8 waves share a 64KB W stage; 2 blocks/CU co-resident so
// staging overlaps compute across blocks). Each wave runs <=1 sixteen-row tile.
// BF16IN: input exact in bf16 => lo(x)=0 => 2 MFMAs/step instead of 3.
template <bool PRELUDE, bool BF16IN, bool BF16OUT>
__global__ __launch_bounds__(512, 4)
void hyp_linear_tan_mfma(const void* __restrict__ xin, const char* __restrict__ gWpack,
                         const float* __restrict__ hb, void* __restrict__ xtan,
                         int n_rows) {
    __shared__ __align__(16) char sW[65536];   // [0,32K)=hi swz, [32K,64K)=lo swz

    const int tid = threadIdx.x;
    const int lane = tid & 63, wid = tid >> 6;
    const int r15 = lane & 15, g = lane >> 4;

    const int tiles = (n_rows + 15) >> 4;
    const int tile = blockIdx.x * 8 + wid;
    const bool active = (tile < tiles);
    const int rowbase = tile << 4;
    const int myrow = rowbase + r15;
    const bool rok = active && (myrow < n_rows);

    // 1) issue x loads first (latency overlaps the staging below)
    float4 xa[4], xb[4];
    uint4 xu[4];
    if (BF16IN) {
        const char* xr = (const char*)xin + (size_t)myrow * 256 + g * 16;
#pragma unroll
        for (int kc = 0; kc < 4; ++kc)
            xu[kc] = rok ? *reinterpret_cast<const uint4*>(xr + kc * 64)
                         : make_uint4(0u, 0u, 0u, 0u);
    } else {
        const float* xr = (const float*)xin + (size_t)myrow * 128 + g * 8;
#pragma unroll
        for (int kc = 0; kc < 4; ++kc) {
            if (rok) {
                xa[kc] = *reinterpret_cast<const float4*>(xr + kc * 32);
                xb[kc] = *reinterpret_cast<const float4*>(xr + kc * 32 + 4);
            } else {
                xa[kc] = make_float4(0.f, 0.f, 0.f, 0.f);
                xb[kc] = xa[kc];
            }
        }
    }

    // 2) stage W pack (64KB / 512 threads = 8 uint4 each)
    {
        const uint4* gsrc = reinterpret_cast<const uint4*>(gWpack);
        uint4* ldst = reinterpret_cast<uint4*>(sW);
#pragma unroll
        for (int i = 0; i < 8; ++i) ldst[tid + i * 512] = gsrc[tid + i * 512];
    }

    // 3) bias fragment: yb[ct] = hb[8*r15 + ct]
    float yb[8];
    {
        const float4 yba = *reinterpret_cast<const float4*>(&hb[r15 * 8]);
        const float4 ybb = *reinterpret_cast<const float4*>(&hb[r15 * 8 + 4]);
        yb[0] = yba.x; yb[1] = yba.y; yb[2] = yba.z; yb[3] = yba.w;
        yb[4] = ybb.x; yb[5] = ybb.y; yb[6] = ybb.z; yb[7] = ybb.w;
    }
    float y2p = 0.f;
#pragma unroll
    for (int t = 0; t < 8; ++t) y2p += yb[t] * yb[t];
#pragma unroll
    for (int off = 1; off < 16; off <<= 1) y2p += __shfl_xor(y2p, off, 64);
    const float y2 = y2p;

    __syncthreads();
    if (!active) return;

    // 4) A-fragments + row norm
    bf16x8 ah[4], al[4];
    float ss = 0.f;
    if (BF16IN) {
#pragma unroll
        for (int kc = 0; kc < 4; ++kc) {
            FragU fu; fu.q = xu[kc];
            ah[kc] = fu.v;
            const uint4 u = xu[kc];
            float f0 = bflo(u.x), f1 = bfhi(u.x), f2_ = bflo(u.y), f3 = bfhi(u.y);
            float f4 = bflo(u.z), f5 = bfhi(u.z), f6 = bflo(u.w), f7 = bfhi(u.w);
            ss += f0 * f0 + f1 * f1 + f2_ * f2_ + f3 * f3
                + f4 * f4 + f5 * f5 + f6 * f6 + f7 * f7;
        }
    } else {
#pragma unroll
        for (int kc = 0; kc < 4; ++kc) {
            const float4 a = xa[kc], b = xb[kc];
            ss += a.x * a.x + a.y * a.y + a.z * a.z + a.w * a.w
                + b.x * b.x + b.y * b.y + b.z * b.z + b.w * b.w;
            ah[kc][0] = (__bf16)a.x; al[kc][0] = (__bf16)(a.x - (float)ah[kc][0]);
            ah[kc][1] = (__bf16)a.y; al[kc][1] = (__bf16)(a.y - (float)ah[kc][1]);
            ah[kc][2] = (__bf16)a.z; al[kc][2] = (__bf16)(a.z - (float)ah[kc][2]);
            ah[kc][3] = (__bf16)a.w; al[kc][3] = (__bf16)(a.w - (float)ah[kc][3]);
            ah[kc][4] = (__bf16)b.x; al[kc][4] = (__bf16)(b.x - (float)ah[kc][4]);
            ah[kc][5] = (__bf16)b.y; al[kc][5] = (__bf16)(b.y - (float)ah[kc][5]);
            ah[kc][6] = (__bf16)b.z; al[kc][6] = (__bf16)(b.z - (float)ah[kc][6]);
            ah[kc][7] = (__bf16)b.w; al[kc][7] = (__bf16)(b.w - (float)ah[kc][7]);
        }
    }
    ss += __shfl_xor(ss, 16, 64);
    ss += __shfl_xor(ss, 32, 64);   // n2 of row rowbase + (lane&15)

    f32x4 acc[8];
#pragma unroll
    for (int ct = 0; ct < 8; ++ct) acc[ct] = (f32x4){0.f, 0.f, 0.f, 0.f};

    const unsigned lswz = (unsigned)((r15 & 7) << 4);
#pragma unroll
    for (int kc = 0; kc < 4; ++kc) {
#pragma unroll
        for (int ct = 0; ct < 8; ++ct) {
            const unsigned byte =
                ((unsigned)((ct << 12) + (r15 << 8) + (kc << 6) + (g << 4))) ^ lswz;
            FragU bh, bl;
            bh.q = *reinterpret_cast<const uint4*>(sW + byte);
            bl.q = *reinterpret_cast<const uint4*>(sW + 32768 + byte);
            acc[ct] = __builtin_amdgcn_mfma_f32_16x16x32_bf16(ah[kc], bh.v, acc[ct], 0, 0, 0);
            acc[ct] = __builtin_amdgcn_mfma_f32_16x16x32_bf16(ah[kc], bl.v, acc[ct], 0, 0, 0);
            if (!BF16IN)
                acc[ct] = __builtin_amdgcn_mfma_f32_16x16x32_bf16(al[kc], bh.v, acc[ct], 0, 0, 0);
        }
    }

    // ---- packed reductions: rawn2 and xyraw per reg-row ----
    float4 r2 = make_float4(0.f, 0.f, 0.f, 0.f);
    float4 xyv = make_float4(0.f, 0.f, 0.f, 0.f);
#pragma unroll
    for (int ct = 0; ct < 8; ++ct) {
        r2.x += acc[ct][0] * acc[ct][0];
        r2.y += acc[ct][1] * acc[ct][1];
        r2.z += acc[ct][2] * acc[ct][2];
        r2.w += acc[ct][3] * acc[ct][3];
        xyv.x += acc[ct][0] * yb[ct];
        xyv.y += acc[ct][1] * yb[ct];
        xyv.z += acc[ct][2] * yb[ct];
        xyv.w += acc[ct][3] * yb[ct];
    }
    red16_f4(r2);
    red16_f4(xyv);

    // ---- per-row scalar chain, ONE row per lane (row = lane&15) ----
    const float rn2 = bcast_row(r2, r15);
    const float xyr = bcast_row(xyv, r15);
    const float n2v = ss;

    const float n = fmaxf(sqrtf(n2v), MIN_NORM);
    float sc = 1.f;
    if (PRELUDE) {
        sc = tanh_fast(n) / n;
        sc *= proj_factor(sc * sc * n2v);
    }
    const float xn = fmaxf(sc * n, MIN_NORM);
    const float mxn = fmaxf(sc * sqrtf(rn2), MIN_NORM);
    const float s = tanh_fast(mxn / xn * artanh_fast(xn));
    const float sl0 = (s * sc) / mxn;
    float m2 = rn2 * sl0 * sl0;
    const float f = proj_factor(m2);
    const float scl = sl0 * f;
    m2 *= f * f;
    const float xy = scl * xyr;
    const float cx = 1.f + 2.f * xy + y2;
    const float cy = 1.f - m2;
    const float rdn = 1.f / fmaxf(1.f + 2.f * xy + m2 * y2, MIN_NORM);
    const float A = cx * scl * rdn;             // o = A*raw + B*yb
    const float B = cy * rdn;
    const float on2 = A * A * rn2 + 2.f * A * B * xyr + B * B * y2;
    const float f2 = proj_factor(on2);
    const float onn = fmaxf(sqrtf(on2) * f2, MIN_NORM);
    const float slg = artanh_fast(onn) / onn;
    const float P = slg * f2 * A;
    const float Q = slg * f2 * B;

#pragma unroll
    for (int reg = 0; reg < 4; ++reg) {
        const float Pr = __shfl(P, 4 * g + reg, 64);
        const float Qr = __shfl(Q, 4 * g + reg, 64);
        const int row = rowbase + 4 * g + reg;
        if (row < n_rows) {
            float v[8];
#pragma unroll
            for (int ct = 0; ct < 8; ++ct)
                v[ct] = fmaf(Pr, acc[ct][reg], Qr * yb[ct]);
            if (BF16OUT) {
                uint4 pk;
                pk.x = (unsigned)f2bf(v[0]) | ((unsigned)f2bf(v[1]) << 16);
                pk.y = (unsigned)f2bf(v[2]) | ((unsigned)f2bf(v[3]) << 16);
                pk.z = (unsigned)f2bf(v[4]) | ((unsigned)f2bf(v[5]) << 16);
                pk.w = (unsigned)f2bf(v[6]) | ((unsigned)f2bf(v[7]) << 16);
                *reinterpret_cast<uint4*>((char*)xtan + (size_t)row * 256 + r15 * 16) = pk;
            } else {
                float* orow = (float*)xtan + (size_t)row * 128 + r15 * 8;
                *reinterpret_cast<float4*>(orow) = make_float4(v[0], v[1], v[2], v[3]);
                *reinterpret_cast<float4*>(orow + 4) = make_float4(v[4], v[5], v[6], v[7]);
            }
        }
    }
}

// ---------------- gather aggregate + fused hyp_act ----------------
// 16 lanes per row (uint4 = 8 bf16 features each). Padded CSR: every row's
// segment length % 4 == 0 and pad entries are {src 0, w +0.0} -> all four
// wave-quarters run identical, branch-free iteration counts.
template <bool BF16OUT>
__global__ __launch_bounds__(256)
void gather_act(const char* __restrict__ xt, const int* __restrict__ ptr,
                const unsigned* __restrict__ epk, void* __restrict__ out, int n_rows) {
    const int v = blockIdx.x * 4 + (threadIdx.x >> 6);
    if (v >= n_rows) return;
    const int lane = threadIdx.x & 63;
    const int q = lane >> 4, t = lane & 15;
    const char* xtl = xt + (t << 4);
    const int beg = ptr[v];
    const int it = (ptr[v + 1] - beg) >> 2;   // identical for all 4 quarters

    float acc[8];
#pragma unroll
    for (int j = 0; j < 8; ++j) acc[j] = 0.f;

    const unsigned* ep = epk + beg + q;
    unsigned p = (it > 0) ? ep[0] : 0u;
    for (int k = 1; k <= it; ++k) {
        const uint4 u = *reinterpret_cast<const uint4*>(xtl + ((p >> 16) << 8));
        const unsigned pn = ep[k * 4];        // buffer has a +16-word tail guard
        const float w = __uint_as_float(p << 16);
        acc[0] = fmaf(w, bflo(u.x), acc[0]);
        acc[1] = fmaf(w, bfhi(u.x), acc[1]);
        acc[2] = fmaf(w, bflo(u.y), acc[2]);
        acc[3] = fmaf(w, bfhi(u.y), acc[3]);
        acc[4] = fmaf(w, bflo(u.z), acc[4]);
        acc[5] = fmaf(w, bfhi(u.z), acc[5]);
        acc[6] = fmaf(w, bflo(u.w), acc[6]);
        acc[7] = fmaf(w, bfhi(u.w), acc[7]);
        p = pn;
    }

    // reduce across quarters: every lane gets full sums for features 8t+j
#pragma unroll
    for (int j = 0; j < 8; ++j) {
        acc[j] += __shfl_xor(acc[j], 16, 64);
        acc[j] += __shfl_xor(acc[j], 32, 64);
    }

    // n2 over the 128 features (partitioned by t; quarters identical)
    float s = 0.f;
#pragma unroll
    for (int j = 0; j < 8; ++j) s += acc[j] * acc[j];
#pragma unroll
    for (int off = 1; off < 16; off <<= 1) s += __shfl_xor(s, off, 64);
    const float n2 = s;

    // h = proj(expmap0(agg)); x = relu(logmap0(h)); out = proj(expmap0(x))
    float n = fmaxf(sqrtf(n2), MIN_NORM);
    float sc = tanh_fast(n) / n;
    float hn2 = sc * sc * n2;
    float f = proj_factor(hn2);
    sc *= f; hn2 *= f * f;
    float hn = fmaxf(sqrtf(hn2), MIN_NORM);
    float sl = artanh_fast(hn) / hn;
    const float scl1 = sc * sl;

    float x[8];
    float s2 = 0.f;
#pragma unroll
    for (int j = 0; j < 8; ++j) {
        x[j] = fmaxf(acc[j] * scl1, 0.f);
        s2 += x[j] * x[j];
    }
#pragma unroll
    for (int off = 1; off < 16; off <<= 1) s2 += __shfl_xor(s2, off, 64);
    float nb = fmaxf(sqrtf(s2), MIN_NORM);
    float scb = tanh_fast(nb) / nb;
    scb *= proj_factor(scb * scb * s2);

    // store: quarter q writes features 8t+2q, 8t+2q+1 (64 lanes cover the row)
    const float o0 = x[2 * q] * scb, o1 = x[2 * q + 1] * scb;
    if (BF16OUT) {
        const unsigned pk = (unsigned)f2bf(o0) | ((unsigned)f2bf(o1) << 16);
        *reinterpret_cast<unsigned*>((char*)out + (size_t)v * 256 + t * 16 + q * 4) = pk;
    } else {
        *reinterpret_cast<float2*>((float*)out + (size_t)v * 128 + t * 8 + q * 2) =
            make_float2(o0, o1);
    }
}

// ---------------- fallback (atomic path, f32 x_tan) ----------------
__global__ __launch_bounds__(256)
void agg_edges(const float* __restrict__ xtan, const int* __restrict__ src,
               const int* __restrict__ dst, const float* __restrict__ ew,
               float* __restrict__ agg, int n_edges) {
    int gt = blockIdx.x * blockDim.x + threadIdx.x;
    int e = gt >> 5;
    if (e >= n_edges) return;
    int c = (gt & 31) << 2;
    int sN = src[e], dN = dst[e];
    float w = ew[e];
    const float4 v = *reinterpret_cast<const float4*>(&xtan[(size_t)sN * 128 + c]);
    float* ap = &agg[(size_t)dN * 128 + c];
    atomicAdd(ap + 0, w * v.x);
    atomicAdd(ap + 1, w * v.y);
    atomicAdd(ap + 2, w * v.z);
    atomicAdd(ap + 3, w * v.w);
}

__global__ __launch_bounds__(256)
void hyp_act_kernel(const float* __restrict__ in, float* __restrict__ out, int n_rows) {
    int row = blockIdx.x * 4 + (threadIdx.x >> 6);
    if (row >= n_rows) return;
    int lane = threadIdx.x & 63;
    int l2 = lane << 1;
    const float2 v = *reinterpret_cast<const float2*>(&in[(size_t)row * 128 + l2]);
    float a0 = v.x, a1 = v.y;
    float n2 = wave_sum(a0 * a0 + a1 * a1);
    float n = fmaxf(sqrtf(n2), MIN_NORM);
    float sc = tanh_fast(n) / n;
    float hn2 = sc * sc * n2;
    float f = proj_factor(hn2);
    sc *= f; hn2 *= f * f;
    float h0 = a0 * sc, h1 = a1 * sc;
    float hn = fmaxf(sqrtf(hn2), MIN_NORM);
    float sl = artanh_fast(hn) / hn;
    float x0 = fmaxf(h0 * sl, 0.f), x1 = fmaxf(h1 * sl, 0.f);
    float n2b = wave_sum(x0 * x0 + x1 * x1);
    float nb = fmaxf(sqrtf(n2b), MIN_NORM);
    float scb = tanh_fast(nb) / nb;
    scb *= proj_factor(scb * scb * n2b);
    *reinterpret_cast<float2*>(&out[(size_t)row * 128 + l2]) =
        make_float2(x0 * scb, x1 * scb);
}

__global__ void bias_kernel(const float* __restrict__ b1, const float* __restrict__ b2,
                            float* __restrict__ hb1, float* __restrict__ hb2) {
    int lane = threadIdx.x;
#pragma unroll
    for (int j = 0; j < 2; ++j) {
        const float* b = j ? b2 : b1;
        float* hb = j ? hb2 : hb1;
        float v0 = b[lane], v1 = b[lane + 64];
        float n2 = wave_sum(v0 * v0 + v1 * v1);
        float n = fmaxf(sqrtf(n2), MIN_NORM);
        float sc = tanh_fast(n) / n;
        sc *= proj_factor(sc * sc * n2);
        hb[lane] = v0 * sc;
        hb[lane + 64] = v1 * sc;
    }
}

__global__ void prep_w(const float* __restrict__ W1, const float* __restrict__ W2,
                       char* __restrict__ g1, char* __restrict__ g2) {
    const int b = blockIdx.x;
    const float* W = (b < 16) ? W1 : W2;
    char* out = (b < 16) ? g1 : g2;
    const int i = (((b & 15) * 256) + threadIdx.x) * 4;
    pack_w4(*reinterpret_cast<const float4*>(&W[i]), i >> 7, i & 127, out);
}

extern "C" void kernel_launch(void* const* d_in, const int* in_sizes, int n_in,
                              void* d_out, int out_size, void* d_ws, size_t ws_size,
                              hipStream_t stream) {
    const float* x   = (const float*)d_in[0];
    const int*   src = (const int*)d_in[1];
    const int*   dst = (const int*)d_in[2];
    const float* ew  = (const float*)d_in[3];
    const float* W1  = (const float*)d_in[4];
    const float* b1  = (const float*)d_in[5];
    const float* W2  = (const float*)d_in[6];
    const float* b2  = (const float*)d_in[7];

    const int N = in_sizes[0] / 128;
    const int E = in_sizes[1];
    float* fout = (float*)d_out;

    const int tiles = (N + 15) >> 4;
    const int lin_grid = (tiles + 7) / 8;     // 8 waves (512 thr) per block
    const int nbE = (E + 255) / 256;
    const int nbN = (N + 255) / 256;

    const size_t epk_words = (size_t)E + 3 * (size_t)N + 16;  // padded CSR + tail guard

    // main-path ws: gW(128K) + hb(1K) + xtA,xtB (bf16) + [epk|cnt] + ptr/cursor/bsum/bscan
    const size_t need = 131072 + 1024
                      + (size_t)N * 256 * 2
                      + (epk_words + N) * 4
                      + ((size_t)(N + 1) + N) * 4
                      + 4096;

    if (ws_size >= need) {
        char*  base  = (char*)d_ws;
        char*  gW1p  = base;
        char*  gW2p  = base + 65536;
        float* hb1   = (float*)(base + 131072);       // 16B-aligned
        float* hb2   = hb1 + 128;
        char*  xtA   = base + 131072 + 1024;          // N*128 bf16
        char*  xtB   = xtA + (size_t)N * 256;         // N*128 bf16
        unsigned* epk = (unsigned*)(xtB + (size_t)N * 256);
        int* cnt     = (int*)(epk + epk_words);       // adjacent: one memset
        int* ptr     = cnt + N;
        int* cursor  = ptr + (N + 1);
        int* bsum    = cursor + N;
        int* bscan   = bsum + 256;                    // 257 ints used

        // zero epk (pads must be {src 0, w 0}) and cnt in one shot
        hipMemsetAsync(epk, 0, (epk_words + N) * 4, stream);
        setup_kernel<<<33 + nbE, 256, 0, stream>>>(W1, W2, gW1p, gW2p,
                                                   b1, b2, hb1, hb2, dst, cnt, E);
        scan1<<<nbN, 256, 0, stream>>>(cnt, ptr, bsum, N);
        scan2<<<1, 256, 0, stream>>>(bsum, bscan, nbN);
        scan3<<<nbN, 256, 0, stream>>>(bscan, ptr, cursor, N);
        scatter_kernel<<<nbE, 256, 0, stream>>>(src, dst, ew, cursor, epk, E);

        // layer 1: x(f32) -> xtA(bf16) -> h1 = xtB(bf16)
        hyp_linear_tan_mfma<true, false, true><<<lin_grid, 512, 0, stream>>>(x, gW1p, hb1, xtA, N);
        gather_act<true><<<(N + 3) / 4, 256, 0, stream>>>(xtA, ptr, epk, xtB, N);
        // layer 2: h1(bf16) -> x_tan2 = xtA(bf16, dead) -> final(f32, d_out)
        hyp_linear_tan_mfma<false, true, true><<<lin_grid, 512, 0, stream>>>(xtB, gW2p, hb2, xtA, N);
        gather_act<false><<<(N + 3) / 4, 256, 0, stream>>>(xtA, ptr, epk, fout, N);
    } else {
        // fallback: f32 atomic-scatter path
        char*  gW1p = (char*)d_ws;
        char*  gW2p = gW1p + 65536;
        float* hb1  = (float*)(gW2p + 65536);
        float* hb2  = hb1 + 128;
        float* nbuf = hb2 + 128;
        const size_t node_bytes = (size_t)N * 128 * sizeof(float);
        const int agg_blocks = (int)(((size_t)E * 32 + 255) / 256);
        const int row_blocks = (N + 3) / 4;

        prep_w<<<32, 256, 0, stream>>>(W1, W2, gW1p, gW2p);
        bias_kernel<<<1, 64, 0, stream>>>(b1, b2, hb1, hb2);
        hyp_linear_tan_mfma<true, false, false><<<lin_grid, 512, 0, stream>>>(x, gW1p, hb1, fout, N);
        hipMemsetAsync(nbuf, 0, node_bytes, stream);
        agg_edges<<<agg_blocks, 256, 0, stream>>>(fout, src, dst, ew, nbuf, E);
        hyp_act_kernel<<<row_blocks, 256, 0, stream>>>(nbuf, nbuf, N);
        hyp_linear_tan_mfma<false, false, false><<<lin_grid, 512, 0, stream>>>(nbuf, gW2p, hb2, fout, N);
        hipMemsetAsync(fout, 0, node_bytes, stream);
        agg_edges<<<agg_blocks, 256, 0, stream>>>(fout, src, dst, ew, nbuf, E);
        hyp_act_kernel<<<row_blocks, 256, 0, stream>>>(nbuf, fout, N);
    }
}